// Round 1
// baseline (217.049 us; speedup 1.0000x reference)
//
#include <hip/hip_runtime.h>
#include <math.h>

#define HH 512
#define WW 1024
#define HWSZ (HH*WW)
#define BB 4
#define TY 8
#define KSIG 11.541560327111707f   /* 8*log2(e) */
#define DD_OFF (BB*3*HWSZ)

__global__ __launch_bounds__(256)
void bokeh_kernel(const float* __restrict__ img,
                  const float* __restrict__ defo,
                  float* __restrict__ out)
{
    // distance table: DT[(ry+13)*7 + |rx|] = fl32(sqrt(ry^2+rx^2)) (correctly
    // rounded via fp64), sentinel 1e30 for |ry|>6 (never read thanks to guards)
    __shared__ float DT[27*7];
    {
        int t = threadIdx.x;
        if (t < 27*7) {
            int ry = t/7 - 13;
            int ax = t - (t/7)*7;
            float v = 1e30f;
            if (ry >= -6 && ry <= 6)
                v = (float)sqrt((double)(ry*ry + ax*ax));
            DT[t] = v;
        }
    }
    __syncthreads();

    const int lane = threadIdx.x & 63;
    const int wv   = threadIdx.x >> 6;
    const int x  = blockIdx.x*64 + lane;          // lane = x -> coalesced
    const int y0 = (blockIdx.y*4 + wv)*TY;        // 8 output rows per thread
    const int b  = blockIdx.z;

    const float* __restrict__ dP = defo + (size_t)b*HWSZ;
    const float* __restrict__ c0 = img + (size_t)(b*3+0)*HWSZ;
    const float* __restrict__ c1 = img + (size_t)(b*3+1)*HWSZ;
    const float* __restrict__ c2 = img + (size_t)(b*3+2)*HWSZ;

    float aW[TY], aR[TY], aG[TY], aB[TY], aD[TY];
#pragma unroll
    for (int k=0;k<TY;++k){aW[k]=0.f;aR[k]=0.f;aG[k]=0.f;aB[k]=0.f;aD[k]=-1e30f;}

    for (int ryy = -6; ryy <= TY+5; ++ryy) {      // src rows (runtime loop)
        const int sy = y0 + ryy;
        if ((unsigned)sy >= (unsigned)HH) continue;   // wave-uniform skip
        const float* __restrict__ dRow = dP + (size_t)sy*WW;
        const float* __restrict__ r0 = c0 + (size_t)sy*WW;
        const float* __restrict__ r1 = c1 + (size_t)sy*WW;
        const float* __restrict__ r2 = c2 + (size_t)sy*WW;
        for (int rx = -6; rx <= 6; ++rx) {        // src col offsets
            const int col = x + rx;
            const bool valid = (unsigned)col < (unsigned)WW;
            const int cc = valid ? col : (col < 0 ? 0 : WW-1); // safe addr
            float d        = dRow[cc];
            const float i0 = r0[cc];
            const float i1 = r1[cc];
            const float i2 = r2[cc];
            d = valid ? d : 0.0f;                 // OOB col: r=0 -> never in circle
            const float r = fabsf(d);
            float ivr = __builtin_amdgcn_rcpf(fmaxf(d*d, 1.0f));
            ivr = valid ? ivr : 0.0f;             // OOB col: exact zero weight
            const float dint = truncf(d);         // == (float)(int)defocus
            const int arx = rx < 0 ? -rx : rx;
            const int tb = (ryy + 13)*7 + arx;
#pragma unroll
            for (int k = 0; k < TY; ++k) {        // this thread's 8 output rows
                const int ry = ryy - k;
                if (ry < -6 || ry > 6) continue;  // wave-uniform branch
                const float Dv = DT[tb - 7*k];    // dist(|ry|,|rx|), broadcast
                const float u = Dv - r;           // u<=0 <=> dist<=r (exact cmp)
                const float e = __builtin_amdgcn_exp2f(u * KSIG);
                const float sig = __builtin_amdgcn_rcpf(1.0f + e); // 0.5+0.5tanh(4(r-d))
                const float w = sig * ivr;
                aW[k] += w;
                aR[k] = fmaf(w, i0, aR[k]);
                aG[k] = fmaf(w, i1, aG[k]);
                aB[k] = fmaf(w, i2, aB[k]);
                const float td = (u <= 0.0f) ? dint : -1e30f;
                aD[k] = fmaxf(aD[k], td);
            }
        }
    }

#pragma unroll
    for (int k=0;k<TY;++k) {
        const int y = y0 + k;
        const float inv = __builtin_amdgcn_rcpf(aW[k]);  // aW >= 0.0139 always
        const size_t o = (size_t)y*WW + x;
        out[(size_t)(b*3+0)*HWSZ + o] = aR[k]*inv;
        out[(size_t)(b*3+1)*HWSZ + o] = aG[k]*inv;
        out[(size_t)(b*3+2)*HWSZ + o] = aB[k]*inv;
        out[DD_OFF + (size_t)b*HWSZ + o] = aD[k];
    }
}

extern "C" void kernel_launch(void* const* d_in, const int* in_sizes, int n_in,
                              void* d_out, int out_size, void* d_ws, size_t ws_size,
                              hipStream_t stream)
{
    const float* img  = (const float*)d_in[0];
    const float* defo = (const float*)d_in[1];
    float* out = (float*)d_out;
    dim3 grid(WW/64, HH/(4*TY), BB);
    bokeh_kernel<<<grid, dim3(256,1,1), 0, stream>>>(img, defo, out);
}